// Round 7
// baseline (154.265 us; speedup 1.0000x reference)
//
#include <hip/hip_runtime.h>

// SparseAttention: B=8, M=N=4096, K=64, R=128 nnz/row (uniform CSR).
// R3/R6: 62.5us at ~88% of aggregate-L2 gather ceiling (1.07 GB compulsory @ ~17 TB/s).
// R5/R6 proved traffic cannot be split to HBM/L3 (nt lines re-hit L2). fp8 fails the
// error budget. R7 micro-opt bundle (bytes unchanged):
//   1. interleaved KV d_ws layout: 256B/(b,col) = [K 128B | V 128B] -> one addr chain/edge
//   2. all-wave redundant softmax -> one fewer barrier, no wave0 serialization
#define Bc 8
#define Mc 4096
#define Nc 4096
#define Kc 64
#define Rc 128

typedef _Float16 h16;
typedef h16 h16x2 __attribute__((ext_vector_type(2)));
typedef h16 h16x8 __attribute__((ext_vector_type(8)));

// fp32 -> fp16 staging into interleaved [K-row | V-row] 256B blocks.
// Thread i handles 8 k-elements of row n_flat = i>>3, chunk j = i&7, for BOTH K and V.
__global__ __launch_bounds__(256) void cvt_kv(
    const float4* __restrict__ K4, const float4* __restrict__ V4,
    h16* __restrict__ KV)
{
    const int i = blockIdx.x * 256 + threadIdx.x;   // 0 .. B*N*K/8-1
    const int nf = i >> 3;                          // flat (b*N+n) row id
    const int j  = i & 7;                           // 8-element chunk in k
    float4 a0 = K4[i * 2], a1 = K4[i * 2 + 1];
    float4 b0 = V4[i * 2], b1 = V4[i * 2 + 1];
    h16x8 kh = { (h16)a0.x,(h16)a0.y,(h16)a0.z,(h16)a0.w,
                 (h16)a1.x,(h16)a1.y,(h16)a1.z,(h16)a1.w };
    h16x8 vh = { (h16)b0.x,(h16)b0.y,(h16)b0.z,(h16)b0.w,
                 (h16)b1.x,(h16)b1.y,(h16)b1.z,(h16)b1.w };
    h16* dst = KV + ((size_t)nf << 7) + j * 8;
    *(h16x8*)dst        = kh;
    *(h16x8*)(dst + 64) = vh;
}

__global__ __launch_bounds__(256) void sattn_kernel(
    const int* __restrict__ cols,    // [M*R], sorted within row
    const float* __restrict__ Q,     // [B,M,K] fp32
    const h16* __restrict__ KV,      // [B,N][K|V] fp16 interleaved 256B blocks
    float* __restrict__ out)         // [B,M,K] fp32
{
    const int b   = blockIdx.x & 7;   // XCD swizzle: one batch's KV (2 MiB) per XCD L2
    const int row = blockIdx.x >> 3;
    const int t   = threadIdx.x;
    const int g   = t >> 3;           // group 0..31 (8 lanes per edge)
    const int ln  = t & 7;            // lane-in-group; owns k = ln*8 .. ln*8+7

    __shared__ float s_w[Rc];                      // logits -> exp(l-m)
    __shared__ __align__(16) float s_part[32][Kc]; // 8 KB partials
    __shared__ __align__(16) float s_red[4][Kc];   // 1 KB stage-2
    __shared__ float s_invden;

    // Per-thread columns for its 4 edges; precompute the single KV base per edge.
    const h16* kvp[4];
    #pragma unroll
    for (int p = 0; p < 4; ++p) {
        const int c = cols[row * Rc + p * 32 + g];
        kvp[p] = KV + ((((size_t)b * Nc + c)) << 7) + ln * 8;
    }

    // Q fragment -> fp16 pairs for fdot2.
    const float4* qp = (const float4*)(Q + (((unsigned)b * Mc + row) << 6) + ln * 8);
    float4 q0 = qp[0], q1 = qp[1];
    h16x2 qh[4];
    qh[0] = h16x2{ (h16)q0.x, (h16)q0.y };
    qh[1] = h16x2{ (h16)q0.z, (h16)q0.w };
    qh[2] = h16x2{ (h16)q1.x, (h16)q1.y };
    qh[3] = h16x2{ (h16)q1.z, (h16)q1.w };

    // ---- SDDMM: K halves of the 4 interleaved blocks ----
    h16x8 kv[4];
    #pragma unroll
    for (int p = 0; p < 4; ++p) kv[p] = *(const h16x8*)kvp[p];

    #pragma unroll
    for (int p = 0; p < 4; ++p) {
        float acc = 0.f;
        #pragma unroll
        for (int j = 0; j < 4; ++j) {
            h16x2 kj = { kv[p][2 * j], kv[p][2 * j + 1] };
            acc = __builtin_amdgcn_fdot2(qh[j], kj, acc, false);
        }
        acc += __shfl_xor(acc, 1, 64);
        acc += __shfl_xor(acc, 2, 64);
        acc += __shfl_xor(acc, 4, 64);
        if (ln == 0) s_w[p * 32 + g] = acc;
    }

    // ---- V prefetch (same blocks, +128B): overlaps the barrier's vmcnt drain ----
    h16x8 vv[4];
    #pragma unroll
    for (int p = 0; p < 4; ++p) vv[p] = *(const h16x8*)(kvp[p] + 64);

    __syncthreads();

    // ---- All-wave redundant softmax: every wave reduces s_w itself; no 2nd barrier
    //      (each wave only consumes values it computed/holds itself). ----
    float e0, e1, invden;
    {
        const int l = t & 63;
        float l0 = s_w[l], l1 = s_w[l + 64];
        float m = fmaxf(l0, l1);
        #pragma unroll
        for (int o = 32; o; o >>= 1) m = fmaxf(m, __shfl_xor(m, o, 64));
        e0 = __expf(l0 - m); e1 = __expf(l1 - m);
        float s = e0 + e1;
        #pragma unroll
        for (int o = 32; o; o >>= 1) s += __shfl_xor(s, o, 64);
        invden = 1.0f / s;
    }
    // This wave needs w for its own 4 edges (slots p*32+g). It holds exps for lanes'
    // (t&63) and (t&63)+64 slots; distribute via s_w (own-wave writes, then in-wave read).
    s_w[t & 63] = e0; s_w[(t & 63) + 64] = e1;   // all waves write identical values
    // NOTE: within a wave, LDS writes complete before subsequent reads (lgkmcnt ordering);
    // values are identical across waves, so cross-wave timing is benign.

    // ---- SPMM ----
    float acc8[8] = {0.f,0.f,0.f,0.f,0.f,0.f,0.f,0.f};
    #pragma unroll
    for (int p = 0; p < 4; ++p) {
        const float w = s_w[p * 32 + g];
        #pragma unroll
        for (int j = 0; j < 8; ++j)
            acc8[j] = fmaf((float)vv[p][j], w, acc8[j]);
    }
    *(float4*)&s_part[g][ln * 8]     = *(float4*)&acc8[0];
    *(float4*)&s_part[g][ln * 8 + 4] = *(float4*)&acc8[4];
    if (t == 0) s_invden = invden;
    __syncthreads();

    // ---- Two-stage cross-group reduction ----
    {
        const int k = t & 63, qq = t >> 6;
        float r = 0.f;
        #pragma unroll
        for (int j = 0; j < 8; ++j) r += s_part[qq * 8 + j][k];
        s_red[qq][k] = r;
    }
    __syncthreads();
    if (t < 64) {
        float r = (s_red[0][t] + s_red[1][t]) + (s_red[2][t] + s_red[3][t]);
        out[(((unsigned)b * Mc + row) << 6) + t] = r * s_invden;
    }
}

extern "C" void kernel_launch(void* const* d_in, const int* in_sizes, int n_in,
                              void* d_out, int out_size, void* d_ws, size_t ws_size,
                              hipStream_t stream) {
    // inputs: 0 row_indices, 1 row_offsets, 2 column_indices, 3 q3d, 4 k3d, 5 v3d, 6 values
    const int*   cols = (const int*)d_in[2];
    const float* Q    = (const float*)d_in[3];
    const float* Km   = (const float*)d_in[4];
    const float* Vm   = (const float*)d_in[5];
    float* out = (float*)d_out;

    h16* KV = (h16*)d_ws;   // 8.39 MB interleaved

    const int nthreads = Bc * Nc * Kc / 8;   // 262144
    cvt_kv<<<dim3(nthreads / 256), dim3(256), 0, stream>>>(
        (const float4*)Km, (const float4*)Vm, KV);
    sattn_kernel<<<dim3(Bc * Mc), dim3(256), 0, stream>>>(cols, Q, KV, out);
}

// Round 8
// 148.849 us; speedup vs baseline: 1.0364x; 1.0364x over previous
//
#include <hip/hip_runtime.h>

// SparseAttention: B=8, M=N=4096, K=64, R=128 nnz/row (uniform CSR).
// FINAL (R3 structure, best measured 62.2-63.3 us):
//   - K/V staged once as fp16 in d_ws (separate contiguous arrays — R7 showed
//     interleaving them into 256B blocks costs ~10% via L2 channel imbalance)
//   - 8 lanes/edge, 16B/lane coalesced gathers; V prefetched before the softmax barrier
//   - XCD swizzle (b = blockIdx & 7) keeps one batch's 2 MiB KV in one XCD's 4 MiB L2
// Measured regime: ~1.07 GB compulsory gather at ~17 TB/s aggregate L2 ≈ 88% of the
// 19.6 TB/s channel model (16ch x 64B x 2.4GHz x 8 XCD). Structural alternatives all
// measured slower: LDS tiling (R4 2.1x), nt HBM-split (R5/R6), layout/softmax (R7).
#define Bc 8
#define Mc 4096
#define Nc 4096
#define Kc 64
#define Rc 128

typedef _Float16 h16;
typedef h16 h16x2 __attribute__((ext_vector_type(2)));
typedef h16 h16x4 __attribute__((ext_vector_type(4)));
typedef h16 h16x8 __attribute__((ext_vector_type(8)));

// fp32 -> fp16 staging for K and V (read 16.8 MB, write 8.4 MB).
__global__ __launch_bounds__(256) void cvt_fp16(
    const float4* __restrict__ K4, const float4* __restrict__ V4,
    h16x4* __restrict__ Kh4, h16x4* __restrict__ Vh4)
{
    const int n4 = Bc * Nc * Kc / 4;  // 524288 float4-groups per tensor
    int i = blockIdx.x * 256 + threadIdx.x;
    const float4* src; h16x4* dst; int idx;
    if (i < n4) { src = K4; dst = Kh4; idx = i; }
    else        { src = V4; dst = Vh4; idx = i - n4; }
    float4 v = src[idx];
    h16x4 o = { (h16)v.x, (h16)v.y, (h16)v.z, (h16)v.w };
    dst[idx] = o;
}

__global__ __launch_bounds__(256) void sattn_kernel(
    const int* __restrict__ cols,    // [M*R], sorted within row
    const float* __restrict__ Q,     // [B,M,K] fp32
    const h16* __restrict__ Kh,      // [B,N,K] fp16 (staged)
    const h16* __restrict__ Vh,      // [B,N,K] fp16 (staged)
    float* __restrict__ out)         // [B,M,K] fp32
{
    const int b   = blockIdx.x & 7;   // XCD swizzle
    const int row = blockIdx.x >> 3;
    const int t   = threadIdx.x;
    const int g   = t >> 3;           // group 0..31 (8 lanes per edge)
    const int ln  = t & 7;            // lane-in-group; handles k = ln*8 .. ln*8+7

    __shared__ float s_w[Rc];                      // logits -> exp(l-m)
    __shared__ __align__(16) float s_part[32][Kc]; // 8 KB partials
    __shared__ __align__(16) float s_red[4][Kc];   // 1 KB stage-2
    __shared__ float s_invden;

    // Per-thread columns for its 4 edges (8 lanes/group read same addr -> broadcast).
    int col4[4];
    #pragma unroll
    for (int p = 0; p < 4; ++p) col4[p] = cols[row * Rc + p * 32 + g];

    // Q fragment: 8 floats at k = ln*8, cvt to fp16 pairs for fdot2.
    const float4* qp = (const float4*)(Q + (((unsigned)b * Mc + row) << 6) + ln * 8);
    float4 q0 = qp[0], q1 = qp[1];
    h16x2 qh[4];
    qh[0] = h16x2{ (h16)q0.x, (h16)q0.y };
    qh[1] = h16x2{ (h16)q0.z, (h16)q0.w };
    qh[2] = h16x2{ (h16)q1.x, (h16)q1.y };
    qh[3] = h16x2{ (h16)q1.z, (h16)q1.w };

    // ---- SDDMM: preload all 4 K fragments (8 rows x 128B per wave-instr, coalesced) ----
    h16x8 kv[4];
    #pragma unroll
    for (int p = 0; p < 4; ++p)
        kv[p] = *(const h16x8*)(Kh + ((((unsigned)b * Nc + col4[p]) << 6) + ln * 8));

    #pragma unroll
    for (int p = 0; p < 4; ++p) {
        float acc = 0.f;
        #pragma unroll
        for (int j = 0; j < 4; ++j) {
            h16x2 kj = { kv[p][2 * j], kv[p][2 * j + 1] };
            acc = __builtin_amdgcn_fdot2(qh[j], kj, acc, false);
        }
        acc += __shfl_xor(acc, 1, 64);
        acc += __shfl_xor(acc, 2, 64);
        acc += __shfl_xor(acc, 4, 64);
        if (ln == 0) s_w[p * 32 + g] = acc;
    }

    // ---- V prefetch: independent of softmax; overlaps the barrier's vmcnt drain ----
    h16x8 vv[4];
    #pragma unroll
    for (int p = 0; p < 4; ++p)
        vv[p] = *(const h16x8*)(Vh + ((((unsigned)b * Nc + col4[p]) << 6) + ln * 8));

    __syncthreads();

    // ---- Softmax over the 128 logits (wave 0) ----
    if (t < 64) {
        float l0 = s_w[t], l1 = s_w[t + 64];
        float m = fmaxf(l0, l1);
        #pragma unroll
        for (int o = 32; o; o >>= 1) m = fmaxf(m, __shfl_xor(m, o, 64));
        float e0 = __expf(l0 - m), e1 = __expf(l1 - m);
        s_w[t] = e0; s_w[t + 64] = e1;
        float s = e0 + e1;
        #pragma unroll
        for (int o = 32; o; o >>= 1) s += __shfl_xor(s, o, 64);
        if (t == 0) s_invden = 1.0f / s;
    }
    __syncthreads();

    // ---- SPMM: acc8[k] += w_e * V[col_e, k] over this group's 4 edges ----
    float acc8[8] = {0.f,0.f,0.f,0.f,0.f,0.f,0.f,0.f};
    #pragma unroll
    for (int p = 0; p < 4; ++p) {
        const float w = s_w[p * 32 + g];
        #pragma unroll
        for (int j = 0; j < 8; ++j)
            acc8[j] = fmaf((float)vv[p][j], w, acc8[j]);
    }
    *(float4*)&s_part[g][ln * 8]     = *(float4*)&acc8[0];
    *(float4*)&s_part[g][ln * 8 + 4] = *(float4*)&acc8[4];
    __syncthreads();

    // ---- Two-stage cross-group reduction (all 256 threads) ----
    {
        const int k = t & 63, qq = t >> 6;
        float r = 0.f;
        #pragma unroll
        for (int j = 0; j < 8; ++j) r += s_part[qq * 8 + j][k];
        s_red[qq][k] = r;
    }
    __syncthreads();
    if (t < 64) {
        float r = (s_red[0][t] + s_red[1][t]) + (s_red[2][t] + s_red[3][t]);
        out[(((unsigned)b * Mc + row) << 6) + t] = r * s_invden;
    }
}

extern "C" void kernel_launch(void* const* d_in, const int* in_sizes, int n_in,
                              void* d_out, int out_size, void* d_ws, size_t ws_size,
                              hipStream_t stream) {
    // inputs: 0 row_indices, 1 row_offsets, 2 column_indices, 3 q3d, 4 k3d, 5 v3d, 6 values
    const int*   cols = (const int*)d_in[2];
    const float* Q    = (const float*)d_in[3];
    const float* Km   = (const float*)d_in[4];
    const float* Vm   = (const float*)d_in[5];
    float* out = (float*)d_out;

    h16* Kh = (h16*)d_ws;
    h16* Vh = Kh + (size_t)Bc * Nc * Kc;   // 4.19 MB each in d_ws

    const int n4 = Bc * Nc * Kc / 4;
    cvt_fp16<<<dim3(2 * n4 / 256), dim3(256), 0, stream>>>(
        (const float4*)Km, (const float4*)Vm, (h16x4*)Kh, (h16x4*)Vh);
    sattn_kernel<<<dim3(Bc * Mc), dim3(256), 0, stream>>>(cols, Q, Kh, Vh, out);
}